// Round 1
// baseline (730.716 us; speedup 1.0000x reference)
//
#include <hip/hip_runtime.h>
#include <stdint.h>

#define NN 100000
#define NE 1600000
#define NF 512
#define NH 128
#define NC 40

typedef float f32x4 __attribute__((ext_vector_type(4)));
typedef short bf16x8 __attribute__((ext_vector_type(8)));

__device__ __forceinline__ unsigned short f2bf(float f){
    unsigned u = __float_as_uint(f);
    u = u + 0x7FFFu + ((u >> 16) & 1u);   // round-to-nearest-even
    return (unsigned short)(u >> 16);
}
__device__ __forceinline__ unsigned pk2(float a, float b){
    return (unsigned)f2bf(a) | ((unsigned)f2bf(b) << 16);
}
__device__ __forceinline__ float bf2f(unsigned short s){
    return __uint_as_float(((unsigned)s) << 16);
}

// ---- prep: W1 -> W1t bf16 [128][512] (transposed), W2 -> W2t bf16 [48][128] (transposed, zero-padded cols 40..47)
__global__ void prep_w(const float* __restrict__ W1, const float* __restrict__ W2,
                       unsigned short* __restrict__ W1t, unsigned short* __restrict__ W2t){
    int tid = blockIdx.x * 256 + threadIdx.x;
    if (tid < NF * NH){
        int c = tid >> 9;        // 0..127
        int k = tid & 511;       // 0..511
        W1t[c * NF + k] = f2bf(W1[k * NH + c]);
    }
    int t2 = tid - NF * NH;
    if (t2 >= 0 && t2 < 48 * NH){
        int c = t2 >> 7;         // 0..47
        int k = t2 & 127;
        W2t[c * NH + k] = (c < NC) ? f2bf(W2[k * NC + c]) : (unsigned short)0;
    }
}

// ---- GEMM1: support1[N][128] (bf16) = x[N][512] @ W1
// 128x128 tile per block (256 thr, 4 waves), BK=32, fp32->bf16 convert during LDS staging.
__global__ __launch_bounds__(256) void gemm1(const float* __restrict__ x,
                                             const unsigned short* __restrict__ W1t,
                                             unsigned short* __restrict__ s1){
    __shared__ unsigned short Al[128 * 40];   // row stride 40 (pad) to break bank conflicts
    __shared__ unsigned short Bl[128 * 40];
    const int tid  = threadIdx.x;
    const int wid  = tid >> 6;
    const int lane = tid & 63;
    const int quad = lane >> 4;
    const int l15  = lane & 15;
    const int br   = blockIdx.x * 128;

    const int r    = tid >> 1;   // 0..127 (row within tile / col of W1t)
    const int half = tid & 1;    // which 16-element half of the 32-k chunk

    int arow = br + r; if (arow >= NN) arow = NN - 1;
    const float* aptr = x + (size_t)arow * NF + half * 16;
    const unsigned short* bptr = W1t + (size_t)r * NF + half * 16;

    f32x4 acc[2][8];
#pragma unroll
    for (int i = 0; i < 2; i++)
#pragma unroll
        for (int j = 0; j < 8; j++) acc[i][j] = (f32x4){0.f, 0.f, 0.f, 0.f};

    for (int ks = 0; ks < NF; ks += 32){
        const float4* ap = (const float4*)(aptr + ks);
        float4 f0 = ap[0], f1 = ap[1], f2 = ap[2], f3 = ap[3];
        const uint4* bp = (const uint4*)(bptr + ks);
        uint4 b0 = bp[0], b1v = bp[1];

        unsigned* Ad = (unsigned*)&Al[r * 40 + half * 16];
        Ad[0] = pk2(f0.x, f0.y); Ad[1] = pk2(f0.z, f0.w);
        Ad[2] = pk2(f1.x, f1.y); Ad[3] = pk2(f1.z, f1.w);
        Ad[4] = pk2(f2.x, f2.y); Ad[5] = pk2(f2.z, f2.w);
        Ad[6] = pk2(f3.x, f3.y); Ad[7] = pk2(f3.z, f3.w);
        uint4* Bd = (uint4*)&Bl[r * 40 + half * 16];
        Bd[0] = b0; Bd[1] = b1v;
        __syncthreads();

        bf16x8 a0 = *(const bf16x8*)&Al[(wid * 32 +      l15) * 40 + quad * 8];
        bf16x8 a1 = *(const bf16x8*)&Al[(wid * 32 + 16 + l15) * 40 + quad * 8];
#pragma unroll
        for (int ct = 0; ct < 8; ct++){
            bf16x8 bb = *(const bf16x8*)&Bl[(ct * 16 + l15) * 40 + quad * 8];
            acc[0][ct] = __builtin_amdgcn_mfma_f32_16x16x32_bf16(a0, bb, acc[0][ct], 0, 0, 0);
            acc[1][ct] = __builtin_amdgcn_mfma_f32_16x16x32_bf16(a1, bb, acc[1][ct], 0, 0, 0);
        }
        __syncthreads();
    }

#pragma unroll
    for (int rt = 0; rt < 2; rt++)
#pragma unroll
        for (int ct = 0; ct < 8; ct++)
#pragma unroll
            for (int i = 0; i < 4; i++){
                int row = br + wid * 32 + rt * 16 + quad * 4 + i;   // C/D: row=(lane>>4)*4+reg
                if (row < NN) s1[(size_t)row * NH + ct * 16 + l15] = f2bf(acc[rt][ct][i]);
            }
}

// ---- CSR build ----
__global__ void hist_k(const int* __restrict__ edst, int* __restrict__ deg){
    int tid = blockIdx.x * 256 + threadIdx.x;
    if (tid < NE) atomicAdd(&deg[edst[tid]], 1);
}

__global__ void scan1(const int* __restrict__ deg, int* __restrict__ rs, int* __restrict__ bsums){
    __shared__ int sh[256];
    int t = threadIdx.x;
    int base = blockIdx.x * 1024 + t * 4;
    int v0 = (base     < NN) ? deg[base]     : 0;
    int v1 = (base + 1 < NN) ? deg[base + 1] : 0;
    int v2 = (base + 2 < NN) ? deg[base + 2] : 0;
    int v3 = (base + 3 < NN) ? deg[base + 3] : 0;
    int ssum = v0 + v1 + v2 + v3;
    sh[t] = ssum;
    __syncthreads();
    for (int o = 1; o < 256; o <<= 1){
        int tmp = (t >= o) ? sh[t - o] : 0;
        __syncthreads();
        sh[t] += tmp;
        __syncthreads();
    }
    int excl = sh[t] - ssum;
    if (base     < NN) rs[base]     = excl; excl += v0;
    if (base + 1 < NN) rs[base + 1] = excl; excl += v1;
    if (base + 2 < NN) rs[base + 2] = excl; excl += v2;
    if (base + 3 < NN) rs[base + 3] = excl;
    if (t == 255) bsums[blockIdx.x] = sh[255];
}

__global__ void scan2(int* __restrict__ bsums){
    __shared__ int sh[128];
    int t = threadIdx.x;
    int v = (t < 98) ? bsums[t] : 0;
    sh[t] = v;
    __syncthreads();
    for (int o = 1; o < 128; o <<= 1){
        int tmp = (t >= o) ? sh[t - o] : 0;
        __syncthreads();
        sh[t] += tmp;
        __syncthreads();
    }
    if (t < 98) bsums[t] = sh[t] - v;   // exclusive block offsets
}

__global__ void scan3(int* __restrict__ rs, const int* __restrict__ bsums){
    int base = blockIdx.x * 1024 + threadIdx.x * 4;
    int add = bsums[blockIdx.x];
#pragma unroll
    for (int i = 0; i < 4; i++)
        if (base + i < NN) rs[base + i] += add;
}

__global__ void scatter_k(const int* __restrict__ esrc, const int* __restrict__ edst,
                          const float* __restrict__ eval, const int* __restrict__ rs,
                          int* __restrict__ deg2, int* __restrict__ psrc, float* __restrict__ pval){
    int tid = blockIdx.x * 256 + threadIdx.x;
    if (tid < NE){
        int d = edst[tid];
        int pos = rs[d] + atomicAdd(&deg2[d], 1);
        psrc[pos] = esrc[tid];
        pval[pos] = eval[tid];
    }
}

// ---- agg1: h[n] = relu(sum_e val*support1[src] + b1), one wave per node, bf16 out
__global__ __launch_bounds__(256) void agg1(const unsigned* __restrict__ s1,
                                            const int* __restrict__ rs,
                                            const int* __restrict__ psrc, const float* __restrict__ pval,
                                            const float* __restrict__ b1, unsigned* __restrict__ h){
    int node = blockIdx.x * 4 + (threadIdx.x >> 6);
    if (node >= NN) return;
    int lane = threadIdx.x & 63;
    int s = rs[node];
    int e = (node == NN - 1) ? NE : rs[node + 1];
    s = __builtin_amdgcn_readfirstlane(s);
    e = __builtin_amdgcn_readfirstlane(e);
    float a0 = 0.f, a1 = 0.f;
    for (int p = s; p < e; p++){
        int src = psrc[p];
        float v = pval[p];
        unsigned u = s1[(size_t)src * 64 + lane];   // 2 bf16 features per lane
        a0 += v * bf2f((unsigned short)(u & 0xffffu));
        a1 += v * bf2f((unsigned short)(u >> 16));
    }
    a0 += b1[2 * lane];     a1 += b1[2 * lane + 1];
    a0 = fmaxf(a0, 0.f);    a1 = fmaxf(a1, 0.f);
    h[(size_t)node * 64 + lane] = pk2(a0, a1);
}

// ---- GEMM2: support2[N][40] (bf16) = h[N][128] @ W2 ; B-frags preloaded in regs, A direct from global
__global__ __launch_bounds__(256) void gemm2(const unsigned short* __restrict__ h,
                                             const unsigned short* __restrict__ W2t,
                                             unsigned short* __restrict__ s2){
    const int tid  = threadIdx.x;
    const int wid  = tid >> 6;
    const int lane = tid & 63;
    const int quad = lane >> 4;
    const int l15  = lane & 15;
    const int row0 = blockIdx.x * 64 + wid * 16;

    bf16x8 bf[3][4];
#pragma unroll
    for (int ct = 0; ct < 3; ct++)
#pragma unroll
        for (int ks = 0; ks < 4; ks++)
            bf[ct][ks] = *(const bf16x8*)&W2t[(ct * 16 + l15) * NH + ks * 32 + quad * 8];

    int arow = row0 + l15; if (arow >= NN) arow = NN - 1;
    const unsigned short* ap = h + (size_t)arow * NH;

    f32x4 acc[3];
#pragma unroll
    for (int ct = 0; ct < 3; ct++) acc[ct] = (f32x4){0.f, 0.f, 0.f, 0.f};
#pragma unroll
    for (int ks = 0; ks < 4; ks++){
        bf16x8 a = *(const bf16x8*)&ap[ks * 32 + quad * 8];
#pragma unroll
        for (int ct = 0; ct < 3; ct++)
            acc[ct] = __builtin_amdgcn_mfma_f32_16x16x32_bf16(a, bf[ct][ks], acc[ct], 0, 0, 0);
    }
#pragma unroll
    for (int ct = 0; ct < 3; ct++)
#pragma unroll
        for (int i = 0; i < 4; i++){
            int row = row0 + quad * 4 + i;
            int col = ct * 16 + l15;
            if (row < NN && col < NC) s2[(size_t)row * NC + col] = f2bf(acc[ct][i]);
        }
}

// ---- agg2 + bias + log_softmax fused: one wave per node
__global__ __launch_bounds__(256) void agg2(const unsigned short* __restrict__ s2,
                                            const int* __restrict__ rs,
                                            const int* __restrict__ psrc, const float* __restrict__ pval,
                                            const float* __restrict__ b2, float* __restrict__ out){
    int node = blockIdx.x * 4 + (threadIdx.x >> 6);
    if (node >= NN) return;
    int lane = threadIdx.x & 63;
    int s = rs[node];
    int e = (node == NN - 1) ? NE : rs[node + 1];
    s = __builtin_amdgcn_readfirstlane(s);
    e = __builtin_amdgcn_readfirstlane(e);
    bool act = lane < NC;
    float a = 0.f;
    for (int p = s; p < e; p++){
        int src = psrc[p];
        float v = pval[p];
        if (act) a += v * bf2f(s2[(size_t)src * NC + lane]);
    }
    float z = act ? (a + b2[lane]) : -INFINITY;
    float m = z;
#pragma unroll
    for (int o = 32; o; o >>= 1) m = fmaxf(m, __shfl_xor(m, o, 64));
    float p = act ? __expf(z - m) : 0.f;
    float ssum = p;
#pragma unroll
    for (int o = 32; o; o >>= 1) ssum += __shfl_xor(ssum, o, 64);
    if (act) out[(size_t)node * NC + lane] = z - m - __logf(ssum);
}

extern "C" void kernel_launch(void* const* d_in, const int* in_sizes, int n_in,
                              void* d_out, int out_size, void* d_ws, size_t ws_size,
                              hipStream_t stream) {
    const float* x    = (const float*)d_in[0];
    const int*   esrc = (const int*)  d_in[1];
    const int*   edst = (const int*)  d_in[2];
    const float* eval = (const float*)d_in[3];
    const float* W1   = (const float*)d_in[4];
    const float* b1   = (const float*)d_in[5];
    const float* W2   = (const float*)d_in[6];
    const float* b2   = (const float*)d_in[7];
    float* out = (float*)d_out;

    char* ws = (char*)d_ws;
    size_t off = 0;
    auto alloc = [&](size_t bytes) -> void* {
        void* p = ws + off;
        off += (bytes + 255) & ~(size_t)255;
        return p;
    };
    unsigned short* W1t  = (unsigned short*)alloc((size_t)NF * NH * 2);
    unsigned short* W2t  = (unsigned short*)alloc((size_t)48 * NH * 2);
    unsigned short* s1   = (unsigned short*)alloc((size_t)NN * NH * 2);  // reused as s2
    unsigned short* h    = (unsigned short*)alloc((size_t)NN * NH * 2);
    int*   deg   = (int*)  alloc((size_t)NN * 4);
    int*   deg2  = (int*)  alloc((size_t)NN * 4);
    int*   rs    = (int*)  alloc((size_t)NN * 4);
    int*   bsums = (int*)  alloc(128 * 4);
    int*   psrc  = (int*)  alloc((size_t)NE * 4);
    float* pval  = (float*)alloc((size_t)NE * 4);
    unsigned short* s2 = s1;

    hipMemsetAsync(deg,  0, (size_t)NN * 4, stream);
    hipMemsetAsync(deg2, 0, (size_t)NN * 4, stream);

    prep_w   <<<280, 256, 0, stream>>>(W1, W2, W1t, W2t);
    gemm1    <<<(NN + 127) / 128, 256, 0, stream>>>(x, W1t, s1);
    hist_k   <<<(NE + 255) / 256, 256, 0, stream>>>(edst, deg);
    scan1    <<<98, 256, 0, stream>>>(deg, rs, bsums);
    scan2    <<<1, 128, 0, stream>>>(bsums);
    scan3    <<<98, 256, 0, stream>>>(rs, bsums);
    scatter_k<<<(NE + 255) / 256, 256, 0, stream>>>(esrc, edst, eval, rs, deg2, psrc, pval);
    agg1     <<<NN / 4, 256, 0, stream>>>((const unsigned*)s1, rs, psrc, pval, b1, (unsigned*)h);
    gemm2    <<<(NN + 63) / 64, 256, 0, stream>>>(h, W2t, s2);
    agg2     <<<NN / 4, 256, 0, stream>>>(s2, rs, psrc, pval, b2, out);
}

// Round 2
// 655.106 us; speedup vs baseline: 1.1154x; 1.1154x over previous
//
#include <hip/hip_runtime.h>
#include <stdint.h>

#define NN 100000
#define NE 1600000
#define NF 512
#define NH 128
#define NC 40

typedef float f32x4 __attribute__((ext_vector_type(4)));
typedef short bf16x8 __attribute__((ext_vector_type(8)));

__device__ __forceinline__ unsigned short f2bf(float f){
    unsigned u = __float_as_uint(f);
    u = u + 0x7FFFu + ((u >> 16) & 1u);   // round-to-nearest-even
    return (unsigned short)(u >> 16);
}
__device__ __forceinline__ unsigned pk2(float a, float b){
    return (unsigned)f2bf(a) | ((unsigned)f2bf(b) << 16);
}
__device__ __forceinline__ float bf2f(unsigned short s){
    return __uint_as_float(((unsigned)s) << 16);
}
__device__ __forceinline__ bf16x8 cvt8(float4 u, float4 v){
    bf16x8 r;
    r[0]=(short)f2bf(u.x); r[1]=(short)f2bf(u.y); r[2]=(short)f2bf(u.z); r[3]=(short)f2bf(u.w);
    r[4]=(short)f2bf(v.x); r[5]=(short)f2bf(v.y); r[6]=(short)f2bf(v.z); r[7]=(short)f2bf(v.w);
    return r;
}

// ---- prep: W1 -> W1t bf16 [128][512] (transposed), W2 -> W2t bf16 [48][128] (transposed, zero-padded)
__global__ void prep_w(const float* __restrict__ W1, const float* __restrict__ W2,
                       unsigned short* __restrict__ W1t, unsigned short* __restrict__ W2t){
    int tid = blockIdx.x * 256 + threadIdx.x;
    if (tid < NF * NH){
        int c = tid >> 9;
        int k = tid & 511;
        W1t[c * NF + k] = f2bf(W1[k * NH + c]);
    }
    int t2 = tid - NF * NH;
    if (t2 >= 0 && t2 < 48 * NH){
        int c = t2 >> 7;
        int k = t2 & 127;
        W2t[c * NH + k] = (c < NC) ? f2bf(W2[k * NC + c]) : (unsigned short)0;
    }
}

// ---- GEMM1: support1[N][128] (bf16) = x[N][512] @ W1
// No LDS, no syncthreads: A-frags loaded straight from global fp32 (the 4 quads of a
// row tile exactly one 128B line per row per K-step), converted in-reg; B-frags from
// L2-resident W1t. 128 rows per block (4 waves x 2 row-tiles).
__global__ __launch_bounds__(256) void gemm1(const float* __restrict__ x,
                                             const unsigned short* __restrict__ W1t,
                                             unsigned short* __restrict__ s1){
    const int tid  = threadIdx.x;
    const int wid  = tid >> 6;
    const int lane = tid & 63;
    const int quad = lane >> 4;
    const int l15  = lane & 15;
    const int br   = blockIdx.x * 128;

    int ra0 = br + wid * 32 + l15;      if (ra0 >= NN) ra0 = NN - 1;
    int ra1 = br + wid * 32 + 16 + l15; if (ra1 >= NN) ra1 = NN - 1;
    const float* a0p = x + (size_t)ra0 * NF + quad * 8;
    const float* a1p = x + (size_t)ra1 * NF + quad * 8;
    const unsigned short* bp = W1t + (size_t)l15 * NF + quad * 8;

    f32x4 acc[2][8];
#pragma unroll
    for (int i = 0; i < 2; i++)
#pragma unroll
        for (int j = 0; j < 8; j++) acc[i][j] = (f32x4){0.f, 0.f, 0.f, 0.f};

    for (int ks = 0; ks < NF; ks += 32){
        float4 fa0 = *(const float4*)(a0p + ks);
        float4 fa1 = *(const float4*)(a0p + ks + 4);
        float4 fb0 = *(const float4*)(a1p + ks);
        float4 fb1 = *(const float4*)(a1p + ks + 4);
        bf16x8 a0 = cvt8(fa0, fa1);
        bf16x8 a1 = cvt8(fb0, fb1);
#pragma unroll
        for (int ct = 0; ct < 8; ct++){
            bf16x8 bb = *(const bf16x8*)(bp + (size_t)ct * 16 * NF + ks);
            acc[0][ct] = __builtin_amdgcn_mfma_f32_16x16x32_bf16(a0, bb, acc[0][ct], 0, 0, 0);
            acc[1][ct] = __builtin_amdgcn_mfma_f32_16x16x32_bf16(a1, bb, acc[1][ct], 0, 0, 0);
        }
    }

#pragma unroll
    for (int rt = 0; rt < 2; rt++)
#pragma unroll
        for (int ct = 0; ct < 8; ct++)
#pragma unroll
            for (int i = 0; i < 4; i++){
                int row = br + wid * 32 + rt * 16 + quad * 4 + i;
                if (row < NN) s1[(size_t)row * NH + ct * 16 + l15] = f2bf(acc[rt][ct][i]);
            }
}

// ---- CSR build ----
__global__ __launch_bounds__(256) void hist_k(const int* __restrict__ edst, int* __restrict__ deg){
    int tid = blockIdx.x * 256 + threadIdx.x;
    if (tid < NE) atomicAdd(&deg[edst[tid]], 1);
}

__global__ void scan1(const int* __restrict__ deg, int* __restrict__ rs, int* __restrict__ bsums){
    __shared__ int sh[256];
    int t = threadIdx.x;
    int base = blockIdx.x * 1024 + t * 4;
    int v0 = (base     < NN) ? deg[base]     : 0;
    int v1 = (base + 1 < NN) ? deg[base + 1] : 0;
    int v2 = (base + 2 < NN) ? deg[base + 2] : 0;
    int v3 = (base + 3 < NN) ? deg[base + 3] : 0;
    int ssum = v0 + v1 + v2 + v3;
    sh[t] = ssum;
    __syncthreads();
    for (int o = 1; o < 256; o <<= 1){
        int tmp = (t >= o) ? sh[t - o] : 0;
        __syncthreads();
        sh[t] += tmp;
        __syncthreads();
    }
    int excl = sh[t] - ssum;
    if (base     < NN) rs[base]     = excl; excl += v0;
    if (base + 1 < NN) rs[base + 1] = excl; excl += v1;
    if (base + 2 < NN) rs[base + 2] = excl; excl += v2;
    if (base + 3 < NN) rs[base + 3] = excl;
    if (t == 255) bsums[blockIdx.x] = sh[255];
}

__global__ void scan2(int* __restrict__ bsums){
    __shared__ int sh[128];
    int t = threadIdx.x;
    int v = (t < 98) ? bsums[t] : 0;
    sh[t] = v;
    __syncthreads();
    for (int o = 1; o < 128; o <<= 1){
        int tmp = (t >= o) ? sh[t - o] : 0;
        __syncthreads();
        sh[t] += tmp;
        __syncthreads();
    }
    if (t < 98) bsums[t] = sh[t] - v;
}

__global__ void scan3(int* __restrict__ rs, const int* __restrict__ bsums){
    int base = blockIdx.x * 1024 + threadIdx.x * 4;
    int add = bsums[blockIdx.x];
#pragma unroll
    for (int i = 0; i < 4; i++)
        if (base + i < NN) rs[base + i] += add;
}

// packed (src, val) record: one random 8B store per edge instead of two 4B stores
__global__ __launch_bounds__(256) void scatter_k(const int* __restrict__ esrc, const int* __restrict__ edst,
                          const float* __restrict__ eval, const int* __restrict__ rs,
                          int* __restrict__ deg2, int2* __restrict__ pk){
    int tid = blockIdx.x * 256 + threadIdx.x;
    if (tid < NE){
        int d = edst[tid];
        int pos = rs[d] + atomicAdd(&deg2[d], 1);
        pk[pos] = make_int2(esrc[tid], __float_as_int(eval[tid]));
    }
}

// ---- agg1: h[n] = relu(sum_e val*support1[src] + b1), one wave per node, unroll-4 gathers
__global__ __launch_bounds__(256) void agg1(const unsigned* __restrict__ s1,
                                            const int* __restrict__ rs,
                                            const int2* __restrict__ pk,
                                            const float* __restrict__ b1, unsigned* __restrict__ h){
    int node = blockIdx.x * 4 + (threadIdx.x >> 6);
    if (node >= NN) return;
    int lane = threadIdx.x & 63;
    int s = __builtin_amdgcn_readfirstlane(rs[node]);
    int e = __builtin_amdgcn_readfirstlane((node == NN - 1) ? NE : rs[node + 1]);
    float a0 = 0.f, a1 = 0.f;
    int p = s;
    for (; p + 4 <= e; p += 4){
        int2 r0 = pk[p], r1 = pk[p + 1], r2 = pk[p + 2], r3 = pk[p + 3];
        unsigned u0 = s1[(size_t)r0.x * 64 + lane];
        unsigned u1 = s1[(size_t)r1.x * 64 + lane];
        unsigned u2 = s1[(size_t)r2.x * 64 + lane];
        unsigned u3 = s1[(size_t)r3.x * 64 + lane];
        float v0 = __int_as_float(r0.y), v1 = __int_as_float(r1.y);
        float v2 = __int_as_float(r2.y), v3 = __int_as_float(r3.y);
        a0 += v0 * bf2f((unsigned short)(u0 & 0xffffu)); a1 += v0 * bf2f((unsigned short)(u0 >> 16));
        a0 += v1 * bf2f((unsigned short)(u1 & 0xffffu)); a1 += v1 * bf2f((unsigned short)(u1 >> 16));
        a0 += v2 * bf2f((unsigned short)(u2 & 0xffffu)); a1 += v2 * bf2f((unsigned short)(u2 >> 16));
        a0 += v3 * bf2f((unsigned short)(u3 & 0xffffu)); a1 += v3 * bf2f((unsigned short)(u3 >> 16));
    }
    for (; p < e; p++){
        int2 r = pk[p];
        float v = __int_as_float(r.y);
        unsigned u = s1[(size_t)r.x * 64 + lane];
        a0 += v * bf2f((unsigned short)(u & 0xffffu));
        a1 += v * bf2f((unsigned short)(u >> 16));
    }
    a0 += b1[2 * lane];     a1 += b1[2 * lane + 1];
    a0 = fmaxf(a0, 0.f);    a1 = fmaxf(a1, 0.f);
    h[(size_t)node * 64 + lane] = pk2(a0, a1);
}

// ---- GEMM2: support2[N][40] (bf16) = h[N][128] @ W2
__global__ __launch_bounds__(256) void gemm2(const unsigned short* __restrict__ h,
                                             const unsigned short* __restrict__ W2t,
                                             unsigned short* __restrict__ s2){
    const int tid  = threadIdx.x;
    const int wid  = tid >> 6;
    const int lane = tid & 63;
    const int quad = lane >> 4;
    const int l15  = lane & 15;
    const int row0 = blockIdx.x * 64 + wid * 16;

    bf16x8 bf[3][4];
#pragma unroll
    for (int ct = 0; ct < 3; ct++)
#pragma unroll
        for (int ks = 0; ks < 4; ks++)
            bf[ct][ks] = *(const bf16x8*)&W2t[(ct * 16 + l15) * NH + ks * 32 + quad * 8];

    int arow = row0 + l15; if (arow >= NN) arow = NN - 1;
    const unsigned short* ap = h + (size_t)arow * NH;

    f32x4 acc[3];
#pragma unroll
    for (int ct = 0; ct < 3; ct++) acc[ct] = (f32x4){0.f, 0.f, 0.f, 0.f};
#pragma unroll
    for (int ks = 0; ks < 4; ks++){
        bf16x8 a = *(const bf16x8*)&ap[ks * 32 + quad * 8];
#pragma unroll
        for (int ct = 0; ct < 3; ct++)
            acc[ct] = __builtin_amdgcn_mfma_f32_16x16x32_bf16(a, bf[ct][ks], acc[ct], 0, 0, 0);
    }
#pragma unroll
    for (int ct = 0; ct < 3; ct++)
#pragma unroll
        for (int i = 0; i < 4; i++){
            int row = row0 + quad * 4 + i;
            int col = ct * 16 + l15;
            if (row < NN && col < NC) s2[(size_t)row * NC + col] = f2bf(acc[ct][i]);
        }
}

// ---- agg2 + bias + log_softmax fused: one wave per node, unroll-4
__global__ __launch_bounds__(256) void agg2(const unsigned short* __restrict__ s2,
                                            const int* __restrict__ rs,
                                            const int2* __restrict__ pk,
                                            const float* __restrict__ b2, float* __restrict__ out){
    int node = blockIdx.x * 4 + (threadIdx.x >> 6);
    if (node >= NN) return;
    int lane = threadIdx.x & 63;
    int s = __builtin_amdgcn_readfirstlane(rs[node]);
    int e = __builtin_amdgcn_readfirstlane((node == NN - 1) ? NE : rs[node + 1]);
    bool act = lane < NC;
    int cl = act ? lane : 0;
    float a = 0.f;
    int p = s;
    for (; p + 4 <= e; p += 4){
        int2 r0 = pk[p], r1 = pk[p + 1], r2 = pk[p + 2], r3 = pk[p + 3];
        float g0 = bf2f(s2[(size_t)r0.x * NC + cl]);
        float g1 = bf2f(s2[(size_t)r1.x * NC + cl]);
        float g2 = bf2f(s2[(size_t)r2.x * NC + cl]);
        float g3 = bf2f(s2[(size_t)r3.x * NC + cl]);
        a += __int_as_float(r0.y) * g0;
        a += __int_as_float(r1.y) * g1;
        a += __int_as_float(r2.y) * g2;
        a += __int_as_float(r3.y) * g3;
    }
    for (; p < e; p++){
        int2 r = pk[p];
        a += __int_as_float(r.y) * bf2f(s2[(size_t)r.x * NC + cl]);
    }
    float z = act ? (a + b2[lane]) : -INFINITY;
    float m = z;
#pragma unroll
    for (int o = 32; o; o >>= 1) m = fmaxf(m, __shfl_xor(m, o, 64));
    float pexp = act ? __expf(z - m) : 0.f;
    float ssum = pexp;
#pragma unroll
    for (int o = 32; o; o >>= 1) ssum += __shfl_xor(ssum, o, 64);
    if (act) out[(size_t)node * NC + lane] = z - m - __logf(ssum);
}

extern "C" void kernel_launch(void* const* d_in, const int* in_sizes, int n_in,
                              void* d_out, int out_size, void* d_ws, size_t ws_size,
                              hipStream_t stream) {
    const float* x    = (const float*)d_in[0];
    const int*   esrc = (const int*)  d_in[1];
    const int*   edst = (const int*)  d_in[2];
    const float* eval = (const float*)d_in[3];
    const float* W1   = (const float*)d_in[4];
    const float* b1   = (const float*)d_in[5];
    const float* W2   = (const float*)d_in[6];
    const float* b2   = (const float*)d_in[7];
    float* out = (float*)d_out;

    char* ws = (char*)d_ws;
    size_t off = 0;
    auto alloc = [&](size_t bytes) -> void* {
        void* p = ws + off;
        off += (bytes + 255) & ~(size_t)255;
        return p;
    };
    unsigned short* W1t  = (unsigned short*)alloc((size_t)NF * NH * 2);
    unsigned short* W2t  = (unsigned short*)alloc((size_t)48 * NH * 2);
    unsigned short* s1   = (unsigned short*)alloc((size_t)NN * NH * 2);  // reused as s2
    unsigned short* h    = (unsigned short*)alloc((size_t)NN * NH * 2);
    int*   deg   = (int*)  alloc((size_t)NN * 4);
    int*   deg2  = (int*)  alloc((size_t)NN * 4);
    int*   rs    = (int*)  alloc((size_t)NN * 4);
    int*   bsums = (int*)  alloc(128 * 4);
    int2*  pk    = (int2*) alloc((size_t)NE * 8);
    unsigned short* s2 = s1;

    hipMemsetAsync(deg,  0, (size_t)NN * 4, stream);
    hipMemsetAsync(deg2, 0, (size_t)NN * 4, stream);

    prep_w   <<<280, 256, 0, stream>>>(W1, W2, W1t, W2t);
    gemm1    <<<(NN + 127) / 128, 256, 0, stream>>>(x, W1t, s1);
    hist_k   <<<(NE + 255) / 256, 256, 0, stream>>>(edst, deg);
    scan1    <<<98, 256, 0, stream>>>(deg, rs, bsums);
    scan2    <<<1, 128, 0, stream>>>(bsums);
    scan3    <<<98, 256, 0, stream>>>(rs, bsums);
    scatter_k<<<(NE + 255) / 256, 256, 0, stream>>>(esrc, edst, eval, rs, deg2, pk);
    agg1     <<<NN / 4, 256, 0, stream>>>((const unsigned*)s1, rs, pk, b1, (unsigned*)h);
    gemm2    <<<(NN + 63) / 64, 256, 0, stream>>>(h, W2t, s2);
    agg2     <<<NN / 4, 256, 0, stream>>>(s2, rs, pk, b2, out);
}

// Round 3
// 614.433 us; speedup vs baseline: 1.1893x; 1.0662x over previous
//
#include <hip/hip_runtime.h>
#include <stdint.h>

#define NN 100000
#define NE 1600000
#define NF 512
#define NH 128
#define NC 40

typedef float f32x4 __attribute__((ext_vector_type(4)));
typedef short bf16x8 __attribute__((ext_vector_type(8)));

__device__ __forceinline__ unsigned short f2bf(float f){
    unsigned u = __float_as_uint(f);
    u = u + 0x7FFFu + ((u >> 16) & 1u);   // round-to-nearest-even
    return (unsigned short)(u >> 16);
}
__device__ __forceinline__ unsigned pk2(float a, float b){
    return (unsigned)f2bf(a) | ((unsigned)f2bf(b) << 16);
}
__device__ __forceinline__ float bf2f(unsigned short s){
    return __uint_as_float(((unsigned)s) << 16);
}
__device__ __forceinline__ float blo(unsigned u){ return __uint_as_float(u << 16); }
__device__ __forceinline__ float bhi(unsigned u){ return __uint_as_float(u & 0xffff0000u); }

// ---- prep: W1 -> W1t bf16 [128][512] (transposed), W2 -> W2t bf16 [48][128] (transposed, zero-padded)
__global__ void prep_w(const float* __restrict__ W1, const float* __restrict__ W2,
                       unsigned short* __restrict__ W1t, unsigned short* __restrict__ W2t){
    int tid = blockIdx.x * 256 + threadIdx.x;
    if (tid < NF * NH){
        int c = tid >> 9;
        int k = tid & 511;
        W1t[c * NF + k] = f2bf(W1[k * NH + c]);
    }
    int t2 = tid - NF * NH;
    if (t2 >= 0 && t2 < 48 * NH){
        int c = t2 >> 7;
        int k = t2 & 127;
        W2t[c * NH + k] = (c < NC) ? f2bf(W2[k * NC + c]) : (unsigned short)0;
    }
}

// ---- GEMM1: support1[N][128] (bf16) = x[N][512] @ W1
// LDS-staged bf16 (convert during staging) + register double-buffer prefetch:
// next K-step's 6 global loads (distinct regs) are issued right after barrier #1
// and fly during the ds_read/MFMA phase. Stride-40 LDS rows: all b128 ops at
// the even 8-phase minimum (2-way aliasing only, which is free).
__global__ __launch_bounds__(256, 3) void gemm1(const float* __restrict__ x,
                                                const unsigned short* __restrict__ W1t,
                                                unsigned short* __restrict__ s1){
    __shared__ unsigned short Al[128 * 40];
    __shared__ unsigned short Bl[128 * 40];
    const int tid  = threadIdx.x;
    const int wid  = tid >> 6;
    const int lane = tid & 63;
    const int quad = lane >> 4;
    const int l15  = lane & 15;
    const int br   = blockIdx.x * 128;

    const int r    = tid >> 1;   // staging row 0..127
    const int half = tid & 1;    // 16-element k-half

    int arow = br + r; if (arow >= NN) arow = NN - 1;
    const float* aptr = x + (size_t)arow * NF + half * 16;
    const unsigned short* bptr = W1t + (size_t)r * NF + half * 16;

    // prefetch registers (distinct, so all 6 loads stay in flight together)
    float4 pa0, pa1, pa2, pa3;
    uint4  pb0, pb1;
    {
        const float4* ap = (const float4*)aptr;
        pa0 = ap[0]; pa1 = ap[1]; pa2 = ap[2]; pa3 = ap[3];
        const uint4* bp = (const uint4*)bptr;
        pb0 = bp[0]; pb1 = bp[1];
    }

    f32x4 acc[2][8];
#pragma unroll
    for (int i = 0; i < 2; i++)
#pragma unroll
        for (int j = 0; j < 8; j++) acc[i][j] = (f32x4){0.f, 0.f, 0.f, 0.f};

    for (int ks = 0; ks < NF; ks += 32){
        // stage prefetched data to LDS (fp32 -> bf16 during staging)
        unsigned* Ad = (unsigned*)&Al[r * 40 + half * 16];
        Ad[0] = pk2(pa0.x, pa0.y); Ad[1] = pk2(pa0.z, pa0.w);
        Ad[2] = pk2(pa1.x, pa1.y); Ad[3] = pk2(pa1.z, pa1.w);
        Ad[4] = pk2(pa2.x, pa2.y); Ad[5] = pk2(pa2.z, pa2.w);
        Ad[6] = pk2(pa3.x, pa3.y); Ad[7] = pk2(pa3.z, pa3.w);
        uint4* Bd = (uint4*)&Bl[r * 40 + half * 16];
        Bd[0] = pb0; Bd[1] = pb1;
        __syncthreads();

        // issue next K-step's global loads NOW; they overlap the MFMA phase
        if (ks + 32 < NF){
            const float4* ap = (const float4*)(aptr + ks + 32);
            pa0 = ap[0]; pa1 = ap[1]; pa2 = ap[2]; pa3 = ap[3];
            const uint4* bp = (const uint4*)(bptr + ks + 32);
            pb0 = bp[0]; pb1 = bp[1];
        }

        bf16x8 a0 = *(const bf16x8*)&Al[(wid * 32 +      l15) * 40 + quad * 8];
        bf16x8 a1 = *(const bf16x8*)&Al[(wid * 32 + 16 + l15) * 40 + quad * 8];
        bf16x8 bb[8];
#pragma unroll
        for (int ct = 0; ct < 8; ct++)
            bb[ct] = *(const bf16x8*)&Bl[(ct * 16 + l15) * 40 + quad * 8];
#pragma unroll
        for (int ct = 0; ct < 8; ct++){
            acc[0][ct] = __builtin_amdgcn_mfma_f32_16x16x32_bf16(a0, bb[ct], acc[0][ct], 0, 0, 0);
            acc[1][ct] = __builtin_amdgcn_mfma_f32_16x16x32_bf16(a1, bb[ct], acc[1][ct], 0, 0, 0);
        }
        __syncthreads();
    }

#pragma unroll
    for (int rt = 0; rt < 2; rt++)
#pragma unroll
        for (int ct = 0; ct < 8; ct++)
#pragma unroll
            for (int i = 0; i < 4; i++){
                int row = br + wid * 32 + rt * 16 + quad * 4 + i;
                if (row < NN) s1[(size_t)row * NH + ct * 16 + l15] = f2bf(acc[rt][ct][i]);
            }
}

// ---- CSR build ----
__global__ __launch_bounds__(256) void hist_k(const int* __restrict__ edst, int* __restrict__ deg){
    int tid = blockIdx.x * 256 + threadIdx.x;
    if (tid < NE) atomicAdd(&deg[edst[tid]], 1);
}

__global__ void scan1(const int* __restrict__ deg, int* __restrict__ rs, int* __restrict__ bsums){
    __shared__ int sh[256];
    int t = threadIdx.x;
    int base = blockIdx.x * 1024 + t * 4;
    int v0 = (base     < NN) ? deg[base]     : 0;
    int v1 = (base + 1 < NN) ? deg[base + 1] : 0;
    int v2 = (base + 2 < NN) ? deg[base + 2] : 0;
    int v3 = (base + 3 < NN) ? deg[base + 3] : 0;
    int ssum = v0 + v1 + v2 + v3;
    sh[t] = ssum;
    __syncthreads();
    for (int o = 1; o < 256; o <<= 1){
        int tmp = (t >= o) ? sh[t - o] : 0;
        __syncthreads();
        sh[t] += tmp;
        __syncthreads();
    }
    int excl = sh[t] - ssum;
    if (base     < NN) rs[base]     = excl; excl += v0;
    if (base + 1 < NN) rs[base + 1] = excl; excl += v1;
    if (base + 2 < NN) rs[base + 2] = excl; excl += v2;
    if (base + 3 < NN) rs[base + 3] = excl;
    if (t == 255) bsums[blockIdx.x] = sh[255];
}

__global__ void scan2(int* __restrict__ bsums){
    __shared__ int sh[128];
    int t = threadIdx.x;
    int v = (t < 98) ? bsums[t] : 0;
    sh[t] = v;
    __syncthreads();
    for (int o = 1; o < 128; o <<= 1){
        int tmp = (t >= o) ? sh[t - o] : 0;
        __syncthreads();
        sh[t] += tmp;
        __syncthreads();
    }
    if (t < 98) bsums[t] = sh[t] - v;
}

__global__ void scan3(int* __restrict__ rs, const int* __restrict__ bsums){
    int base = blockIdx.x * 1024 + threadIdx.x * 4;
    int add = bsums[blockIdx.x];
#pragma unroll
    for (int i = 0; i < 4; i++)
        if (base + i < NN) rs[base + i] += add;
}

__global__ __launch_bounds__(256) void scatter_k(const int* __restrict__ esrc, const int* __restrict__ edst,
                          const float* __restrict__ eval, const int* __restrict__ rs,
                          int* __restrict__ deg2, int2* __restrict__ pk){
    int tid = blockIdx.x * 256 + threadIdx.x;
    if (tid < NE){
        int d = edst[tid];
        int pos = rs[d] + atomicAdd(&deg2[d], 1);
        pk[pos] = make_int2(esrc[tid], __float_as_int(eval[tid]));
    }
}

// ---- agg1: h[n] = relu(sum_e val*support1[src] + b1)
// one wave per node; pk records loaded once per 64-edge chunk (coalesced, one
// load per lane) then shfl-broadcast; gathers unrolled x8 into independent regs.
__global__ __launch_bounds__(256) void agg1(const unsigned* __restrict__ s1v,
                                            const int* __restrict__ rs,
                                            const int2* __restrict__ pk,
                                            const float* __restrict__ b1, unsigned* __restrict__ h){
    int node = blockIdx.x * 4 + (threadIdx.x >> 6);
    if (node >= NN) return;
    int lane = threadIdx.x & 63;
    int s = __builtin_amdgcn_readfirstlane(rs[node]);
    int e = __builtin_amdgcn_readfirstlane((node == NN - 1) ? NE : rs[node + 1]);
    float a0 = 0.f, a1 = 0.f;
    for (int base = s; base < e; base += 64){
        int cnt = e - base; if (cnt > 64) cnt = 64;
        int2 rec = make_int2(0, 0);
        if (base + lane < e) rec = pk[base + lane];
        int j = 0;
        for (; j + 8 <= cnt; j += 8){
            int i0 = __shfl(rec.x, j + 0, 64), i1 = __shfl(rec.x, j + 1, 64);
            int i2 = __shfl(rec.x, j + 2, 64), i3 = __shfl(rec.x, j + 3, 64);
            int i4 = __shfl(rec.x, j + 4, 64), i5 = __shfl(rec.x, j + 5, 64);
            int i6 = __shfl(rec.x, j + 6, 64), i7 = __shfl(rec.x, j + 7, 64);
            unsigned u0 = s1v[(size_t)i0 * 64 + lane];
            unsigned u1 = s1v[(size_t)i1 * 64 + lane];
            unsigned u2 = s1v[(size_t)i2 * 64 + lane];
            unsigned u3 = s1v[(size_t)i3 * 64 + lane];
            unsigned u4 = s1v[(size_t)i4 * 64 + lane];
            unsigned u5 = s1v[(size_t)i5 * 64 + lane];
            unsigned u6 = s1v[(size_t)i6 * 64 + lane];
            unsigned u7 = s1v[(size_t)i7 * 64 + lane];
            float v0 = __int_as_float(__shfl(rec.y, j + 0, 64));
            float v1 = __int_as_float(__shfl(rec.y, j + 1, 64));
            float v2 = __int_as_float(__shfl(rec.y, j + 2, 64));
            float v3 = __int_as_float(__shfl(rec.y, j + 3, 64));
            float v4 = __int_as_float(__shfl(rec.y, j + 4, 64));
            float v5 = __int_as_float(__shfl(rec.y, j + 5, 64));
            float v6 = __int_as_float(__shfl(rec.y, j + 6, 64));
            float v7 = __int_as_float(__shfl(rec.y, j + 7, 64));
            a0 += v0 * blo(u0); a1 += v0 * bhi(u0);
            a0 += v1 * blo(u1); a1 += v1 * bhi(u1);
            a0 += v2 * blo(u2); a1 += v2 * bhi(u2);
            a0 += v3 * blo(u3); a1 += v3 * bhi(u3);
            a0 += v4 * blo(u4); a1 += v4 * bhi(u4);
            a0 += v5 * blo(u5); a1 += v5 * bhi(u5);
            a0 += v6 * blo(u6); a1 += v6 * bhi(u6);
            a0 += v7 * blo(u7); a1 += v7 * bhi(u7);
        }
        for (; j < cnt; j++){
            int   i0 = __shfl(rec.x, j, 64);
            float v0 = __int_as_float(__shfl(rec.y, j, 64));
            unsigned u0 = s1v[(size_t)i0 * 64 + lane];
            a0 += v0 * blo(u0); a1 += v0 * bhi(u0);
        }
    }
    a0 += b1[2 * lane];     a1 += b1[2 * lane + 1];
    a0 = fmaxf(a0, 0.f);    a1 = fmaxf(a1, 0.f);
    h[(size_t)node * 64 + lane] = pk2(a0, a1);
}

// ---- GEMM2: support2[N][40] (bf16) = h[N][128] @ W2
__global__ __launch_bounds__(256) void gemm2(const unsigned short* __restrict__ h,
                                             const unsigned short* __restrict__ W2t,
                                             unsigned short* __restrict__ s2){
    const int tid  = threadIdx.x;
    const int wid  = tid >> 6;
    const int lane = tid & 63;
    const int quad = lane >> 4;
    const int l15  = lane & 15;
    const int row0 = blockIdx.x * 64 + wid * 16;

    bf16x8 bf[3][4];
#pragma unroll
    for (int ct = 0; ct < 3; ct++)
#pragma unroll
        for (int ks = 0; ks < 4; ks++)
            bf[ct][ks] = *(const bf16x8*)&W2t[(ct * 16 + l15) * NH + ks * 32 + quad * 8];

    int arow = row0 + l15; if (arow >= NN) arow = NN - 1;
    const unsigned short* ap = h + (size_t)arow * NH;

    bf16x8 a[4];
#pragma unroll
    for (int ks = 0; ks < 4; ks++) a[ks] = *(const bf16x8*)&ap[ks * 32 + quad * 8];

    f32x4 acc[3];
#pragma unroll
    for (int ct = 0; ct < 3; ct++) acc[ct] = (f32x4){0.f, 0.f, 0.f, 0.f};
#pragma unroll
    for (int ks = 0; ks < 4; ks++)
#pragma unroll
        for (int ct = 0; ct < 3; ct++)
            acc[ct] = __builtin_amdgcn_mfma_f32_16x16x32_bf16(a[ks], bf[ct][ks], acc[ct], 0, 0, 0);

#pragma unroll
    for (int ct = 0; ct < 3; ct++)
#pragma unroll
        for (int i = 0; i < 4; i++){
            int row = row0 + quad * 4 + i;
            int col = ct * 16 + l15;
            if (row < NN && col < NC) s2[(size_t)row * NC + col] = f2bf(acc[ct][i]);
        }
}

// ---- agg2 + bias + log_softmax fused: one wave per node, shfl-broadcast + x8 gathers
__global__ __launch_bounds__(256) void agg2(const unsigned short* __restrict__ s2,
                                            const int* __restrict__ rs,
                                            const int2* __restrict__ pk,
                                            const float* __restrict__ b2, float* __restrict__ out){
    int node = blockIdx.x * 4 + (threadIdx.x >> 6);
    if (node >= NN) return;
    int lane = threadIdx.x & 63;
    int s = __builtin_amdgcn_readfirstlane(rs[node]);
    int e = __builtin_amdgcn_readfirstlane((node == NN - 1) ? NE : rs[node + 1]);
    bool act = lane < NC;
    int cl = act ? lane : 0;
    float a = 0.f;
    for (int base = s; base < e; base += 64){
        int cnt = e - base; if (cnt > 64) cnt = 64;
        int2 rec = make_int2(0, 0);
        if (base + lane < e) rec = pk[base + lane];
        int j = 0;
        for (; j + 8 <= cnt; j += 8){
            int i0 = __shfl(rec.x, j + 0, 64), i1 = __shfl(rec.x, j + 1, 64);
            int i2 = __shfl(rec.x, j + 2, 64), i3 = __shfl(rec.x, j + 3, 64);
            int i4 = __shfl(rec.x, j + 4, 64), i5 = __shfl(rec.x, j + 5, 64);
            int i6 = __shfl(rec.x, j + 6, 64), i7 = __shfl(rec.x, j + 7, 64);
            float g0 = bf2f(s2[(size_t)i0 * NC + cl]);
            float g1 = bf2f(s2[(size_t)i1 * NC + cl]);
            float g2 = bf2f(s2[(size_t)i2 * NC + cl]);
            float g3 = bf2f(s2[(size_t)i3 * NC + cl]);
            float g4 = bf2f(s2[(size_t)i4 * NC + cl]);
            float g5 = bf2f(s2[(size_t)i5 * NC + cl]);
            float g6 = bf2f(s2[(size_t)i6 * NC + cl]);
            float g7 = bf2f(s2[(size_t)i7 * NC + cl]);
            a += __int_as_float(__shfl(rec.y, j + 0, 64)) * g0;
            a += __int_as_float(__shfl(rec.y, j + 1, 64)) * g1;
            a += __int_as_float(__shfl(rec.y, j + 2, 64)) * g2;
            a += __int_as_float(__shfl(rec.y, j + 3, 64)) * g3;
            a += __int_as_float(__shfl(rec.y, j + 4, 64)) * g4;
            a += __int_as_float(__shfl(rec.y, j + 5, 64)) * g5;
            a += __int_as_float(__shfl(rec.y, j + 6, 64)) * g6;
            a += __int_as_float(__shfl(rec.y, j + 7, 64)) * g7;
        }
        for (; j < cnt; j++){
            int   i0 = __shfl(rec.x, j, 64);
            float v0 = __int_as_float(__shfl(rec.y, j, 64));
            a += v0 * bf2f(s2[(size_t)i0 * NC + cl]);
        }
    }
    float z = act ? (a + b2[lane]) : -INFINITY;
    float m = z;
#pragma unroll
    for (int o = 32; o; o >>= 1) m = fmaxf(m, __shfl_xor(m, o, 64));
    float pexp = act ? __expf(z - m) : 0.f;
    float ssum = pexp;
#pragma unroll
    for (int o = 32; o; o >>= 1) ssum += __shfl_xor(ssum, o, 64);
    if (act) out[(size_t)node * NC + lane] = z - m - __logf(ssum);
}

extern "C" void kernel_launch(void* const* d_in, const int* in_sizes, int n_in,
                              void* d_out, int out_size, void* d_ws, size_t ws_size,
                              hipStream_t stream) {
    const float* x    = (const float*)d_in[0];
    const int*   esrc = (const int*)  d_in[1];
    const int*   edst = (const int*)  d_in[2];
    const float* eval = (const float*)d_in[3];
    const float* W1   = (const float*)d_in[4];
    const float* b1   = (const float*)d_in[5];
    const float* W2   = (const float*)d_in[6];
    const float* b2   = (const float*)d_in[7];
    float* out = (float*)d_out;

    char* ws = (char*)d_ws;
    size_t off = 0;
    auto alloc = [&](size_t bytes) -> void* {
        void* p = ws + off;
        off += (bytes + 255) & ~(size_t)255;
        return p;
    };
    unsigned short* W1t  = (unsigned short*)alloc((size_t)NF * NH * 2);
    unsigned short* W2t  = (unsigned short*)alloc((size_t)48 * NH * 2);
    unsigned short* s1   = (unsigned short*)alloc((size_t)NN * NH * 2);  // reused as s2
    unsigned short* h    = (unsigned short*)alloc((size_t)NN * NH * 2);
    int*   deg   = (int*)  alloc((size_t)NN * 4);
    int*   deg2  = (int*)  alloc((size_t)NN * 4);
    int*   rs    = (int*)  alloc((size_t)NN * 4);
    int*   bsums = (int*)  alloc(128 * 4);
    int2*  pk    = (int2*) alloc((size_t)NE * 8);
    unsigned short* s2 = s1;

    hipMemsetAsync(deg,  0, (size_t)NN * 4, stream);
    hipMemsetAsync(deg2, 0, (size_t)NN * 4, stream);

    prep_w   <<<280, 256, 0, stream>>>(W1, W2, W1t, W2t);
    gemm1    <<<(NN + 127) / 128, 256, 0, stream>>>(x, W1t, s1);
    hist_k   <<<(NE + 255) / 256, 256, 0, stream>>>(edst, deg);
    scan1    <<<98, 256, 0, stream>>>(deg, rs, bsums);
    scan2    <<<1, 128, 0, stream>>>(bsums);
    scan3    <<<98, 256, 0, stream>>>(rs, bsums);
    scatter_k<<<(NE + 255) / 256, 256, 0, stream>>>(esrc, edst, eval, rs, deg2, pk);
    agg1     <<<NN / 4, 256, 0, stream>>>((const unsigned*)s1, rs, pk, b1, (unsigned*)h);
    gemm2    <<<(NN + 63) / 64, 256, 0, stream>>>(h, W2t, s2);
    agg2     <<<NN / 4, 256, 0, stream>>>(s2, rs, pk, b2, out);
}

// Round 4
// 574.667 us; speedup vs baseline: 1.2715x; 1.0692x over previous
//
#include <hip/hip_runtime.h>
#include <stdint.h>

#define NN 100000
#define NE 1600000
#define NF 512
#define NH 128
#define NC 40

typedef float f32x4 __attribute__((ext_vector_type(4)));
typedef short bf16x8 __attribute__((ext_vector_type(8)));

__device__ __forceinline__ unsigned short f2bf(float f){
    unsigned u = __float_as_uint(f);
    u = u + 0x7FFFu + ((u >> 16) & 1u);   // round-to-nearest-even
    return (unsigned short)(u >> 16);
}
__device__ __forceinline__ unsigned pk2(float a, float b){
    return (unsigned)f2bf(a) | ((unsigned)f2bf(b) << 16);
}
__device__ __forceinline__ float bf2f(unsigned short s){
    return __uint_as_float(((unsigned)s) << 16);
}
__device__ __forceinline__ float blo(unsigned u){ return __uint_as_float(u << 16); }
__device__ __forceinline__ float bhi(unsigned u){ return __uint_as_float(u & 0xffff0000u); }

// ---- fused: weight prep (blocks 0..279) + degree histogram with position record
// posw[e] = this edge's rank among edges sharing its dst (from the atomic's return)
__global__ __launch_bounds__(256) void hist_prep(const int* __restrict__ edst,
                       int* __restrict__ deg, int* __restrict__ posw,
                       const float* __restrict__ W1, const float* __restrict__ W2,
                       unsigned short* __restrict__ W1t, unsigned short* __restrict__ W2t){
    if (blockIdx.x < 280){
        int tid = blockIdx.x * 256 + threadIdx.x;
        if (tid < NF * NH){
            int c = tid >> 9;
            int k = tid & 511;
            W1t[c * NF + k] = f2bf(W1[k * NH + c]);
        }
        int t2 = tid - NF * NH;
        if (t2 >= 0 && t2 < 48 * NH){
            int c = t2 >> 7;
            int k = t2 & 127;
            W2t[c * NH + k] = (c < NC) ? f2bf(W2[k * NC + c]) : (unsigned short)0;
        }
    } else {
        int tid = (blockIdx.x - 280) * 256 + threadIdx.x;
        if (tid < NE){
            int d = edst[tid];
            posw[tid] = atomicAdd(&deg[d], 1);
        }
    }
}

// ---- GEMM1: support1[N][128] (bf16) = x[N][512] @ W1
// LDS-staged bf16 + register double-buffer prefetch (round-3 proven version).
__global__ __launch_bounds__(256, 3) void gemm1(const float* __restrict__ x,
                                                const unsigned short* __restrict__ W1t,
                                                unsigned short* __restrict__ s1){
    __shared__ unsigned short Al[128 * 40];
    __shared__ unsigned short Bl[128 * 40];
    const int tid  = threadIdx.x;
    const int wid  = tid >> 6;
    const int lane = tid & 63;
    const int quad = lane >> 4;
    const int l15  = lane & 15;
    const int br   = blockIdx.x * 128;

    const int r    = tid >> 1;
    const int half = tid & 1;

    int arow = br + r; if (arow >= NN) arow = NN - 1;
    const float* aptr = x + (size_t)arow * NF + half * 16;
    const unsigned short* bptr = W1t + (size_t)r * NF + half * 16;

    float4 pa0, pa1, pa2, pa3;
    uint4  pb0, pb1;
    {
        const float4* ap = (const float4*)aptr;
        pa0 = ap[0]; pa1 = ap[1]; pa2 = ap[2]; pa3 = ap[3];
        const uint4* bp = (const uint4*)bptr;
        pb0 = bp[0]; pb1 = bp[1];
    }

    f32x4 acc[2][8];
#pragma unroll
    for (int i = 0; i < 2; i++)
#pragma unroll
        for (int j = 0; j < 8; j++) acc[i][j] = (f32x4){0.f, 0.f, 0.f, 0.f};

    for (int ks = 0; ks < NF; ks += 32){
        unsigned* Ad = (unsigned*)&Al[r * 40 + half * 16];
        Ad[0] = pk2(pa0.x, pa0.y); Ad[1] = pk2(pa0.z, pa0.w);
        Ad[2] = pk2(pa1.x, pa1.y); Ad[3] = pk2(pa1.z, pa1.w);
        Ad[4] = pk2(pa2.x, pa2.y); Ad[5] = pk2(pa2.z, pa2.w);
        Ad[6] = pk2(pa3.x, pa3.y); Ad[7] = pk2(pa3.z, pa3.w);
        uint4* Bd = (uint4*)&Bl[r * 40 + half * 16];
        Bd[0] = pb0; Bd[1] = pb1;
        __syncthreads();

        if (ks + 32 < NF){
            const float4* ap = (const float4*)(aptr + ks + 32);
            pa0 = ap[0]; pa1 = ap[1]; pa2 = ap[2]; pa3 = ap[3];
            const uint4* bp = (const uint4*)(bptr + ks + 32);
            pb0 = bp[0]; pb1 = bp[1];
        }

        bf16x8 a0 = *(const bf16x8*)&Al[(wid * 32 +      l15) * 40 + quad * 8];
        bf16x8 a1 = *(const bf16x8*)&Al[(wid * 32 + 16 + l15) * 40 + quad * 8];
        bf16x8 bb[8];
#pragma unroll
        for (int ct = 0; ct < 8; ct++)
            bb[ct] = *(const bf16x8*)&Bl[(ct * 16 + l15) * 40 + quad * 8];
#pragma unroll
        for (int ct = 0; ct < 8; ct++){
            acc[0][ct] = __builtin_amdgcn_mfma_f32_16x16x32_bf16(a0, bb[ct], acc[0][ct], 0, 0, 0);
            acc[1][ct] = __builtin_amdgcn_mfma_f32_16x16x32_bf16(a1, bb[ct], acc[1][ct], 0, 0, 0);
        }
        __syncthreads();
    }

#pragma unroll
    for (int rt = 0; rt < 2; rt++)
#pragma unroll
        for (int ct = 0; ct < 8; ct++)
#pragma unroll
            for (int i = 0; i < 4; i++){
                int row = br + wid * 32 + rt * 16 + quad * 4 + i;
                if (row < NN) s1[(size_t)row * NH + ct * 16 + l15] = f2bf(acc[rt][ct][i]);
            }
}

// ---- scan over degrees (per-block), bsums[b] = block total
__global__ void scan1(const int* __restrict__ deg, int* __restrict__ rs, int* __restrict__ bsums){
    __shared__ int sh[256];
    int t = threadIdx.x;
    int base = blockIdx.x * 1024 + t * 4;
    int v0 = (base     < NN) ? deg[base]     : 0;
    int v1 = (base + 1 < NN) ? deg[base + 1] : 0;
    int v2 = (base + 2 < NN) ? deg[base + 2] : 0;
    int v3 = (base + 3 < NN) ? deg[base + 3] : 0;
    int ssum = v0 + v1 + v2 + v3;
    sh[t] = ssum;
    __syncthreads();
    for (int o = 1; o < 256; o <<= 1){
        int tmp = (t >= o) ? sh[t - o] : 0;
        __syncthreads();
        sh[t] += tmp;
        __syncthreads();
    }
    int excl = sh[t] - ssum;
    if (base     < NN) rs[base]     = excl; excl += v0;
    if (base + 1 < NN) rs[base + 1] = excl; excl += v1;
    if (base + 2 < NN) rs[base + 2] = excl; excl += v2;
    if (base + 3 < NN) rs[base + 3] = excl;
    if (t == 255) bsums[blockIdx.x] = sh[255];
}

// ---- apply cross-block prefix: each block wave-reduces bsums[0..blockIdx) itself
__global__ void scan3(int* __restrict__ rs, const int* __restrict__ bsums){
    __shared__ int add_s;
    int t = threadIdx.x;
    if (t < 64){
        int v = 0;
        if (t      < blockIdx.x) v  = bsums[t];
        if (t + 64 < blockIdx.x) v += bsums[t + 64];
#pragma unroll
        for (int o = 32; o; o >>= 1) v += __shfl_xor(v, o, 64);
        if (t == 0) add_s = v;
    }
    __syncthreads();
    int add = add_s;
    int base = blockIdx.x * 1024 + t * 4;
#pragma unroll
    for (int i = 0; i < 4; i++)
        if (base + i < NN) rs[base + i] += add;
}

// ---- scatter: no atomic — position comes from rs[dst] + posw[e]
__global__ __launch_bounds__(256) void scatter_k(const int* __restrict__ esrc, const int* __restrict__ edst,
                          const float* __restrict__ eval, const int* __restrict__ rs,
                          const int* __restrict__ posw, int2* __restrict__ pk){
    int tid = blockIdx.x * 256 + threadIdx.x;
    if (tid < NE){
        int d = edst[tid];
        int pos = rs[d] + posw[tid];
        pk[pos] = make_int2(esrc[tid], __float_as_int(eval[tid]));
    }
}

// ---- agg1: h[n] = relu(sum_e val*support1[src] + b1)
// one wave per node; pk loaded coalesced once per 64-edge chunk, shfl-broadcast;
// gathers unrolled x8 into independent regs (each gather = exactly two full 128B lines).
__global__ __launch_bounds__(256) void agg1(const unsigned* __restrict__ s1v,
                                            const int* __restrict__ rs,
                                            const int2* __restrict__ pk,
                                            const float* __restrict__ b1, unsigned* __restrict__ h){
    int node = blockIdx.x * 4 + (threadIdx.x >> 6);
    if (node >= NN) return;
    int lane = threadIdx.x & 63;
    int s = __builtin_amdgcn_readfirstlane(rs[node]);
    int e = __builtin_amdgcn_readfirstlane((node == NN - 1) ? NE : rs[node + 1]);
    float a0 = 0.f, a1 = 0.f;
    for (int base = s; base < e; base += 64){
        int cnt = e - base; if (cnt > 64) cnt = 64;
        int2 rec = make_int2(0, 0);
        if (base + lane < e) rec = pk[base + lane];
        int j = 0;
        for (; j + 8 <= cnt; j += 8){
            int i0 = __shfl(rec.x, j + 0, 64), i1 = __shfl(rec.x, j + 1, 64);
            int i2 = __shfl(rec.x, j + 2, 64), i3 = __shfl(rec.x, j + 3, 64);
            int i4 = __shfl(rec.x, j + 4, 64), i5 = __shfl(rec.x, j + 5, 64);
            int i6 = __shfl(rec.x, j + 6, 64), i7 = __shfl(rec.x, j + 7, 64);
            unsigned u0 = s1v[(size_t)i0 * 64 + lane];
            unsigned u1 = s1v[(size_t)i1 * 64 + lane];
            unsigned u2 = s1v[(size_t)i2 * 64 + lane];
            unsigned u3 = s1v[(size_t)i3 * 64 + lane];
            unsigned u4 = s1v[(size_t)i4 * 64 + lane];
            unsigned u5 = s1v[(size_t)i5 * 64 + lane];
            unsigned u6 = s1v[(size_t)i6 * 64 + lane];
            unsigned u7 = s1v[(size_t)i7 * 64 + lane];
            float v0 = __int_as_float(__shfl(rec.y, j + 0, 64));
            float v1 = __int_as_float(__shfl(rec.y, j + 1, 64));
            float v2 = __int_as_float(__shfl(rec.y, j + 2, 64));
            float v3 = __int_as_float(__shfl(rec.y, j + 3, 64));
            float v4 = __int_as_float(__shfl(rec.y, j + 4, 64));
            float v5 = __int_as_float(__shfl(rec.y, j + 5, 64));
            float v6 = __int_as_float(__shfl(rec.y, j + 6, 64));
            float v7 = __int_as_float(__shfl(rec.y, j + 7, 64));
            a0 += v0 * blo(u0); a1 += v0 * bhi(u0);
            a0 += v1 * blo(u1); a1 += v1 * bhi(u1);
            a0 += v2 * blo(u2); a1 += v2 * bhi(u2);
            a0 += v3 * blo(u3); a1 += v3 * bhi(u3);
            a0 += v4 * blo(u4); a1 += v4 * bhi(u4);
            a0 += v5 * blo(u5); a1 += v5 * bhi(u5);
            a0 += v6 * blo(u6); a1 += v6 * bhi(u6);
            a0 += v7 * blo(u7); a1 += v7 * bhi(u7);
        }
        for (; j < cnt; j++){
            int   i0 = __shfl(rec.x, j, 64);
            float v0 = __int_as_float(__shfl(rec.y, j, 64));
            unsigned u0 = s1v[(size_t)i0 * 64 + lane];
            a0 += v0 * blo(u0); a1 += v0 * bhi(u0);
        }
    }
    a0 += b1[2 * lane];     a1 += b1[2 * lane + 1];
    a0 = fmaxf(a0, 0.f);    a1 = fmaxf(a1, 0.f);
    h[(size_t)node * 64 + lane] = pk2(a0, a1);
}

// ---- GEMM2: s2p[N][64] (bf16, row-padded to 128B) = h[N][128] @ W2
__global__ __launch_bounds__(256) void gemm2(const unsigned short* __restrict__ h,
                                             const unsigned short* __restrict__ W2t,
                                             unsigned short* __restrict__ s2p){
    const int tid  = threadIdx.x;
    const int wid  = tid >> 6;
    const int lane = tid & 63;
    const int quad = lane >> 4;
    const int l15  = lane & 15;
    const int row0 = blockIdx.x * 64 + wid * 16;

    bf16x8 bf[3][4];
#pragma unroll
    for (int ct = 0; ct < 3; ct++)
#pragma unroll
        for (int ks = 0; ks < 4; ks++)
            bf[ct][ks] = *(const bf16x8*)&W2t[(ct * 16 + l15) * NH + ks * 32 + quad * 8];

    int arow = row0 + l15; if (arow >= NN) arow = NN - 1;
    const unsigned short* ap = h + (size_t)arow * NH;

    bf16x8 a[4];
#pragma unroll
    for (int ks = 0; ks < 4; ks++) a[ks] = *(const bf16x8*)&ap[ks * 32 + quad * 8];

    f32x4 acc[3];
#pragma unroll
    for (int ct = 0; ct < 3; ct++) acc[ct] = (f32x4){0.f, 0.f, 0.f, 0.f};
#pragma unroll
    for (int ks = 0; ks < 4; ks++)
#pragma unroll
        for (int ct = 0; ct < 3; ct++)
            acc[ct] = __builtin_amdgcn_mfma_f32_16x16x32_bf16(a[ks], bf[ct][ks], acc[ct], 0, 0, 0);

    // cols 40..47 are exact zeros (W2t zero-padded); cols 48..63 never read by active lanes
#pragma unroll
    for (int ct = 0; ct < 3; ct++)
#pragma unroll
        for (int i = 0; i < 4; i++){
            int row = row0 + quad * 4 + i;
            if (row < NN) s2p[(size_t)row * 64 + ct * 16 + l15] = f2bf(acc[ct][i]);
        }
}

// ---- agg2 + bias + log_softmax fused: one wave per node; each gather = one aligned 128B line
__global__ __launch_bounds__(256) void agg2(const unsigned short* __restrict__ s2p,
                                            const int* __restrict__ rs,
                                            const int2* __restrict__ pk,
                                            const float* __restrict__ b2, float* __restrict__ out){
    int node = blockIdx.x * 4 + (threadIdx.x >> 6);
    if (node >= NN) return;
    int lane = threadIdx.x & 63;
    int s = __builtin_amdgcn_readfirstlane(rs[node]);
    int e = __builtin_amdgcn_readfirstlane((node == NN - 1) ? NE : rs[node + 1]);
    float a = 0.f;
    for (int base = s; base < e; base += 64){
        int cnt = e - base; if (cnt > 64) cnt = 64;
        int2 rec = make_int2(0, 0);
        if (base + lane < e) rec = pk[base + lane];
        int j = 0;
        for (; j + 8 <= cnt; j += 8){
            int i0 = __shfl(rec.x, j + 0, 64), i1 = __shfl(rec.x, j + 1, 64);
            int i2 = __shfl(rec.x, j + 2, 64), i3 = __shfl(rec.x, j + 3, 64);
            int i4 = __shfl(rec.x, j + 4, 64), i5 = __shfl(rec.x, j + 5, 64);
            int i6 = __shfl(rec.x, j + 6, 64), i7 = __shfl(rec.x, j + 7, 64);
            float g0 = bf2f(s2p[(size_t)i0 * 64 + lane]);
            float g1 = bf2f(s2p[(size_t)i1 * 64 + lane]);
            float g2 = bf2f(s2p[(size_t)i2 * 64 + lane]);
            float g3 = bf2f(s2p[(size_t)i3 * 64 + lane]);
            float g4 = bf2f(s2p[(size_t)i4 * 64 + lane]);
            float g5 = bf2f(s2p[(size_t)i5 * 64 + lane]);
            float g6 = bf2f(s2p[(size_t)i6 * 64 + lane]);
            float g7 = bf2f(s2p[(size_t)i7 * 64 + lane]);
            a += __int_as_float(__shfl(rec.y, j + 0, 64)) * g0;
            a += __int_as_float(__shfl(rec.y, j + 1, 64)) * g1;
            a += __int_as_float(__shfl(rec.y, j + 2, 64)) * g2;
            a += __int_as_float(__shfl(rec.y, j + 3, 64)) * g3;
            a += __int_as_float(__shfl(rec.y, j + 4, 64)) * g4;
            a += __int_as_float(__shfl(rec.y, j + 5, 64)) * g5;
            a += __int_as_float(__shfl(rec.y, j + 6, 64)) * g6;
            a += __int_as_float(__shfl(rec.y, j + 7, 64)) * g7;
        }
        for (; j < cnt; j++){
            int   i0 = __shfl(rec.x, j, 64);
            float v0 = __int_as_float(__shfl(rec.y, j, 64));
            a += v0 * bf2f(s2p[(size_t)i0 * 64 + lane]);
        }
    }
    bool act = lane < NC;
    float z = act ? (a + b2[lane]) : -INFINITY;
    float m = z;
#pragma unroll
    for (int o = 32; o; o >>= 1) m = fmaxf(m, __shfl_xor(m, o, 64));
    float pexp = act ? __expf(z - m) : 0.f;
    float ssum = pexp;
#pragma unroll
    for (int o = 32; o; o >>= 1) ssum += __shfl_xor(ssum, o, 64);
    if (act) out[(size_t)node * NC + lane] = z - m - __logf(ssum);
}

extern "C" void kernel_launch(void* const* d_in, const int* in_sizes, int n_in,
                              void* d_out, int out_size, void* d_ws, size_t ws_size,
                              hipStream_t stream) {
    const float* x    = (const float*)d_in[0];
    const int*   esrc = (const int*)  d_in[1];
    const int*   edst = (const int*)  d_in[2];
    const float* eval = (const float*)d_in[3];
    const float* W1   = (const float*)d_in[4];
    const float* b1   = (const float*)d_in[5];
    const float* W2   = (const float*)d_in[6];
    const float* b2   = (const float*)d_in[7];
    float* out = (float*)d_out;

    char* ws = (char*)d_ws;
    size_t off = 0;
    auto alloc = [&](size_t bytes) -> void* {
        void* p = ws + off;
        off += (bytes + 255) & ~(size_t)255;
        return p;
    };
    unsigned short* W1t  = (unsigned short*)alloc((size_t)NF * NH * 2);
    unsigned short* W2t  = (unsigned short*)alloc((size_t)48 * NH * 2);
    unsigned short* s1   = (unsigned short*)alloc((size_t)NN * NH * 2);
    unsigned short* h    = (unsigned short*)alloc((size_t)NN * NH * 2);
    unsigned short* s2p  = (unsigned short*)alloc((size_t)NN * 64 * 2);
    int*   deg   = (int*)  alloc((size_t)NN * 4);
    int*   rs    = (int*)  alloc((size_t)NN * 4);
    int*   bsums = (int*)  alloc(128 * 4);
    int*   posw  = (int*)  alloc((size_t)NE * 4);
    int2*  pk    = (int2*) alloc((size_t)NE * 8);

    hipMemsetAsync(deg, 0, (size_t)NN * 4, stream);

    hist_prep<<<280 + (NE + 255) / 256, 256, 0, stream>>>(edst, deg, posw, W1, W2, W1t, W2t);
    gemm1    <<<(NN + 127) / 128, 256, 0, stream>>>(x, W1t, s1);
    scan1    <<<98, 256, 0, stream>>>(deg, rs, bsums);
    scan3    <<<98, 256, 0, stream>>>(rs, bsums);
    scatter_k<<<(NE + 255) / 256, 256, 0, stream>>>(esrc, edst, eval, rs, posw, pk);
    agg1     <<<NN / 4, 256, 0, stream>>>((const unsigned*)s1, rs, pk, b1, (unsigned*)h);
    gemm2    <<<(NN + 63) / 64, 256, 0, stream>>>(h, W2t, s2p);
    agg2     <<<NN / 4, 256, 0, stream>>>(s2p, rs, pk, b2, out);
}

// Round 5
// 553.484 us; speedup vs baseline: 1.3202x; 1.0383x over previous
//
#include <hip/hip_runtime.h>
#include <stdint.h>

#define NN 100000
#define NE 1600000
#define NF 512
#define NH 128
#define NC 40

typedef float f32x4 __attribute__((ext_vector_type(4)));
typedef short bf16x8 __attribute__((ext_vector_type(8)));

__device__ __forceinline__ unsigned short f2bf(float f){
    unsigned u = __float_as_uint(f);
    u = u + 0x7FFFu + ((u >> 16) & 1u);   // round-to-nearest-even
    return (unsigned short)(u >> 16);
}
__device__ __forceinline__ unsigned pk2(float a, float b){
    return (unsigned)f2bf(a) | ((unsigned)f2bf(b) << 16);
}
__device__ __forceinline__ float bf2f(unsigned short s){
    return __uint_as_float(((unsigned)s) << 16);
}
__device__ __forceinline__ float blo(unsigned u){ return __uint_as_float(u << 16); }
__device__ __forceinline__ float bhi(unsigned u){ return __uint_as_float(u & 0xffff0000u); }

// ---- fused: weight prep (blocks 0..279) + degree histogram with position record
__global__ __launch_bounds__(256) void hist_prep(const int* __restrict__ edst,
                       int* __restrict__ deg, int* __restrict__ posw,
                       const float* __restrict__ W1, const float* __restrict__ W2,
                       unsigned short* __restrict__ W1t, unsigned short* __restrict__ W2t){
    if (blockIdx.x < 280){
        int tid = blockIdx.x * 256 + threadIdx.x;
        if (tid < NF * NH){
            int c = tid >> 9;
            int k = tid & 511;
            W1t[c * NF + k] = f2bf(W1[k * NH + c]);
        }
        int t2 = tid - NF * NH;
        if (t2 >= 0 && t2 < 48 * NH){
            int c = t2 >> 7;
            int k = t2 & 127;
            W2t[c * NH + k] = (c < NC) ? f2bf(W2[k * NC + c]) : (unsigned short)0;
        }
    } else {
        int tid = (blockIdx.x - 280) * 256 + threadIdx.x;
        if (tid < NE){
            int d = edst[tid];
            posw[tid] = atomicAdd(&deg[d], 1);
        }
    }
}

// ---- GEMM1: support1[N][128] (bf16) = x[N][512] @ W1
// LDS double-buffered: stage K-step k+1 into buf^1 while MFMAing buf — ONE barrier
// per K-step (vs 2). 40 KB LDS -> still 3-4 blocks/CU.
__global__ __launch_bounds__(256, 3) void gemm1(const float* __restrict__ x,
                                                const unsigned short* __restrict__ W1t,
                                                unsigned short* __restrict__ s1){
    __shared__ unsigned short Al[2][128 * 40];
    __shared__ unsigned short Bl[2][128 * 40];
    const int tid  = threadIdx.x;
    const int wid  = tid >> 6;
    const int lane = tid & 63;
    const int quad = lane >> 4;
    const int l15  = lane & 15;
    const int br   = blockIdx.x * 128;

    const int r    = tid >> 1;
    const int half = tid & 1;

    int arow = br + r; if (arow >= NN) arow = NN - 1;
    const float* aptr = x + (size_t)arow * NF + half * 16;
    const unsigned short* bptr = W1t + (size_t)r * NF + half * 16;

    float4 pa0, pa1, pa2, pa3;
    uint4  pb0, pb1;
    // load + stage K-step 0
    {
        const float4* ap = (const float4*)aptr;
        pa0 = ap[0]; pa1 = ap[1]; pa2 = ap[2]; pa3 = ap[3];
        const uint4* bp = (const uint4*)bptr;
        pb0 = bp[0]; pb1 = bp[1];
        unsigned* Ad = (unsigned*)&Al[0][r * 40 + half * 16];
        Ad[0] = pk2(pa0.x, pa0.y); Ad[1] = pk2(pa0.z, pa0.w);
        Ad[2] = pk2(pa1.x, pa1.y); Ad[3] = pk2(pa1.z, pa1.w);
        Ad[4] = pk2(pa2.x, pa2.y); Ad[5] = pk2(pa2.z, pa2.w);
        Ad[6] = pk2(pa3.x, pa3.y); Ad[7] = pk2(pa3.z, pa3.w);
        uint4* Bd = (uint4*)&Bl[0][r * 40 + half * 16];
        Bd[0] = pb0; Bd[1] = pb1;
    }
    __syncthreads();

    f32x4 acc[2][8];
#pragma unroll
    for (int i = 0; i < 2; i++)
#pragma unroll
        for (int j = 0; j < 8; j++) acc[i][j] = (f32x4){0.f, 0.f, 0.f, 0.f};

    int cur = 0;
    for (int ks = 0; ks < NF; ks += 32){
        const bool more = (ks + 32 < NF);
        if (more){
            const float4* ap = (const float4*)(aptr + ks + 32);
            pa0 = ap[0]; pa1 = ap[1]; pa2 = ap[2]; pa3 = ap[3];
            const uint4* bp = (const uint4*)(bptr + ks + 32);
            pb0 = bp[0]; pb1 = bp[1];
        }

        bf16x8 a0 = *(const bf16x8*)&Al[cur][(wid * 32 +      l15) * 40 + quad * 8];
        bf16x8 a1 = *(const bf16x8*)&Al[cur][(wid * 32 + 16 + l15) * 40 + quad * 8];
        bf16x8 bb[8];
#pragma unroll
        for (int ct = 0; ct < 8; ct++)
            bb[ct] = *(const bf16x8*)&Bl[cur][(ct * 16 + l15) * 40 + quad * 8];
#pragma unroll
        for (int ct = 0; ct < 8; ct++){
            acc[0][ct] = __builtin_amdgcn_mfma_f32_16x16x32_bf16(a0, bb[ct], acc[0][ct], 0, 0, 0);
            acc[1][ct] = __builtin_amdgcn_mfma_f32_16x16x32_bf16(a1, bb[ct], acc[1][ct], 0, 0, 0);
        }

        if (more){
            int nxt = cur ^ 1;
            unsigned* Ad = (unsigned*)&Al[nxt][r * 40 + half * 16];
            Ad[0] = pk2(pa0.x, pa0.y); Ad[1] = pk2(pa0.z, pa0.w);
            Ad[2] = pk2(pa1.x, pa1.y); Ad[3] = pk2(pa1.z, pa1.w);
            Ad[4] = pk2(pa2.x, pa2.y); Ad[5] = pk2(pa2.z, pa2.w);
            Ad[6] = pk2(pa3.x, pa3.y); Ad[7] = pk2(pa3.z, pa3.w);
            uint4* Bd = (uint4*)&Bl[nxt][r * 40 + half * 16];
            Bd[0] = pb0; Bd[1] = pb1;
        }
        __syncthreads();
        cur ^= 1;
    }

#pragma unroll
    for (int rt = 0; rt < 2; rt++)
#pragma unroll
        for (int ct = 0; ct < 8; ct++)
#pragma unroll
            for (int i = 0; i < 4; i++){
                int row = br + wid * 32 + rt * 16 + quad * 4 + i;
                if (row < NN) s1[(size_t)row * NH + ct * 16 + l15] = f2bf(acc[rt][ct][i]);
            }
}

// ---- scan over degrees (per-block), bsums[b] = block total
__global__ void scan1(const int* __restrict__ deg, int* __restrict__ rs, int* __restrict__ bsums){
    __shared__ int sh[256];
    int t = threadIdx.x;
    int base = blockIdx.x * 1024 + t * 4;
    int v0 = (base     < NN) ? deg[base]     : 0;
    int v1 = (base + 1 < NN) ? deg[base + 1] : 0;
    int v2 = (base + 2 < NN) ? deg[base + 2] : 0;
    int v3 = (base + 3 < NN) ? deg[base + 3] : 0;
    int ssum = v0 + v1 + v2 + v3;
    sh[t] = ssum;
    __syncthreads();
    for (int o = 1; o < 256; o <<= 1){
        int tmp = (t >= o) ? sh[t - o] : 0;
        __syncthreads();
        sh[t] += tmp;
        __syncthreads();
    }
    int excl = sh[t] - ssum;
    if (base     < NN) rs[base]     = excl; excl += v0;
    if (base + 1 < NN) rs[base + 1] = excl; excl += v1;
    if (base + 2 < NN) rs[base + 2] = excl; excl += v2;
    if (base + 3 < NN) rs[base + 3] = excl;
    if (t == 255) bsums[blockIdx.x] = sh[255];
}

// ---- apply cross-block prefix
__global__ void scan3(int* __restrict__ rs, const int* __restrict__ bsums){
    __shared__ int add_s;
    int t = threadIdx.x;
    if (t < 64){
        int v = 0;
        if (t      < blockIdx.x) v  = bsums[t];
        if (t + 64 < blockIdx.x) v += bsums[t + 64];
#pragma unroll
        for (int o = 32; o; o >>= 1) v += __shfl_xor(v, o, 64);
        if (t == 0) add_s = v;
    }
    __syncthreads();
    int add = add_s;
    int base = blockIdx.x * 1024 + t * 4;
#pragma unroll
    for (int i = 0; i < 4; i++)
        if (base + i < NN) rs[base + i] += add;
}

// ---- scatter: no atomic — position from rs[dst] + posw[e]
__global__ __launch_bounds__(256) void scatter_k(const int* __restrict__ esrc, const int* __restrict__ edst,
                          const float* __restrict__ eval, const int* __restrict__ rs,
                          const int* __restrict__ posw, int2* __restrict__ pk){
    int tid = blockIdx.x * 256 + threadIdx.x;
    if (tid < NE){
        int d = edst[tid];
        int pos = rs[d] + posw[tid];
        pk[pos] = make_int2(esrc[tid], __float_as_int(eval[tid]));
    }
}

// ---- agg1: h[n] = relu(sum_e val*support1[src] + b1)
// TWO nodes per wave (32 lanes each); uint2 gathers (half-wave covers the full
// 256B row); pk loaded coalesced per 32-edge chunk per half, shfl-broadcast;
// x8 unroll -> 16 gathers in flight per wave.
__global__ __launch_bounds__(256) void agg1(const uint2* __restrict__ s1v,
                                            const int* __restrict__ rs,
                                            const int2* __restrict__ pk,
                                            const float* __restrict__ b1, uint2* __restrict__ h){
    const int lane  = threadIdx.x & 63;
    const int half  = lane >> 5;
    const int hl    = lane & 31;
    const int lbase = half * 32;
    const int node  = blockIdx.x * 8 + (threadIdx.x >> 6) * 2 + half;   // NN%8==0

    int s = rs[node];
    int e = (node == NN - 1) ? NE : rs[node + 1];
    float a0 = 0.f, a1 = 0.f, a2 = 0.f, a3 = 0.f;

    for (int base = s; base < e; base += 32){
        int cnt = e - base; if (cnt > 32) cnt = 32;
        int2 rec = make_int2(0, 0);
        if (hl < cnt) rec = pk[base + hl];
        int j = 0;
        for (; j + 8 <= cnt; j += 8){
            int is[8];
#pragma unroll
            for (int q = 0; q < 8; q++) is[q] = __shfl(rec.x, lbase + j + q, 64);
            uint2 us[8];
#pragma unroll
            for (int q = 0; q < 8; q++) us[q] = s1v[(size_t)is[q] * 32 + hl];
            float vs[8];
#pragma unroll
            for (int q = 0; q < 8; q++) vs[q] = __int_as_float(__shfl(rec.y, lbase + j + q, 64));
#pragma unroll
            for (int q = 0; q < 8; q++){
                a0 += vs[q] * blo(us[q].x); a1 += vs[q] * bhi(us[q].x);
                a2 += vs[q] * blo(us[q].y); a3 += vs[q] * bhi(us[q].y);
            }
        }
        for (; j < cnt; j++){
            int   i0 = __shfl(rec.x, lbase + j, 64);
            float v0 = __int_as_float(__shfl(rec.y, lbase + j, 64));
            uint2 u  = s1v[(size_t)i0 * 32 + hl];
            a0 += v0 * blo(u.x); a1 += v0 * bhi(u.x);
            a2 += v0 * blo(u.y); a3 += v0 * bhi(u.y);
        }
    }
    a0 += b1[4 * hl];     a1 += b1[4 * hl + 1];
    a2 += b1[4 * hl + 2]; a3 += b1[4 * hl + 3];
    a0 = fmaxf(a0, 0.f); a1 = fmaxf(a1, 0.f);
    a2 = fmaxf(a2, 0.f); a3 = fmaxf(a3, 0.f);
    h[(size_t)node * 32 + hl] = make_uint2(pk2(a0, a1), pk2(a2, a3));
}

// ---- GEMM2: s2p[N][64] (bf16, row-padded to 128B) = h[N][128] @ W2
__global__ __launch_bounds__(256) void gemm2(const unsigned short* __restrict__ h,
                                             const unsigned short* __restrict__ W2t,
                                             unsigned short* __restrict__ s2p){
    const int tid  = threadIdx.x;
    const int wid  = tid >> 6;
    const int lane = tid & 63;
    const int quad = lane >> 4;
    const int l15  = lane & 15;
    const int row0 = blockIdx.x * 64 + wid * 16;

    bf16x8 bf[3][4];
#pragma unroll
    for (int ct = 0; ct < 3; ct++)
#pragma unroll
        for (int ks = 0; ks < 4; ks++)
            bf[ct][ks] = *(const bf16x8*)&W2t[(ct * 16 + l15) * NH + ks * 32 + quad * 8];

    int arow = row0 + l15; if (arow >= NN) arow = NN - 1;
    const unsigned short* ap = h + (size_t)arow * NH;

    bf16x8 a[4];
#pragma unroll
    for (int ks = 0; ks < 4; ks++) a[ks] = *(const bf16x8*)&ap[ks * 32 + quad * 8];

    f32x4 acc[3];
#pragma unroll
    for (int ct = 0; ct < 3; ct++) acc[ct] = (f32x4){0.f, 0.f, 0.f, 0.f};
#pragma unroll
    for (int ks = 0; ks < 4; ks++)
#pragma unroll
        for (int ct = 0; ct < 3; ct++)
            acc[ct] = __builtin_amdgcn_mfma_f32_16x16x32_bf16(a[ks], bf[ct][ks], acc[ct], 0, 0, 0);

#pragma unroll
    for (int ct = 0; ct < 3; ct++)
#pragma unroll
        for (int i = 0; i < 4; i++){
            int row = row0 + quad * 4 + i;
            if (row < NN) s2p[(size_t)row * 64 + ct * 16 + l15] = f2bf(acc[ct][i]);
        }
}

// ---- agg2 + bias + log_softmax: TWO nodes per wave; u32 gather covers the
// 128B padded row per half; lanes hl<20 hold 2 classes each; reduce within half.
__global__ __launch_bounds__(256) void agg2(const unsigned* __restrict__ s2v,
                                            const int* __restrict__ rs,
                                            const int2* __restrict__ pk,
                                            const float* __restrict__ b2, float* __restrict__ out){
    const int lane  = threadIdx.x & 63;
    const int half  = lane >> 5;
    const int hl    = lane & 31;
    const int lbase = half * 32;
    const int node  = blockIdx.x * 8 + (threadIdx.x >> 6) * 2 + half;

    int s = rs[node];
    int e = (node == NN - 1) ? NE : rs[node + 1];
    float a0 = 0.f, a1 = 0.f;

    for (int base = s; base < e; base += 32){
        int cnt = e - base; if (cnt > 32) cnt = 32;
        int2 rec = make_int2(0, 0);
        if (hl < cnt) rec = pk[base + hl];
        int j = 0;
        for (; j + 8 <= cnt; j += 8){
            int is[8];
#pragma unroll
            for (int q = 0; q < 8; q++) is[q] = __shfl(rec.x, lbase + j + q, 64);
            unsigned us[8];
#pragma unroll
            for (int q = 0; q < 8; q++) us[q] = s2v[(size_t)is[q] * 32 + hl];
            float vs[8];
#pragma unroll
            for (int q = 0; q < 8; q++) vs[q] = __int_as_float(__shfl(rec.y, lbase + j + q, 64));
#pragma unroll
            for (int q = 0; q < 8; q++){
                a0 += vs[q] * blo(us[q]); a1 += vs[q] * bhi(us[q]);
            }
        }
        for (; j < cnt; j++){
            int   i0 = __shfl(rec.x, lbase + j, 64);
            float v0 = __int_as_float(__shfl(rec.y, lbase + j, 64));
            unsigned u = s2v[(size_t)i0 * 32 + hl];
            a0 += v0 * blo(u); a1 += v0 * bhi(u);
        }
    }
    bool act = hl < 20;   // cols 2*hl, 2*hl+1 < 40
    float z0 = act ? (a0 + b2[2 * hl])     : -INFINITY;
    float z1 = act ? (a1 + b2[2 * hl + 1]) : -INFINITY;
    float m = fmaxf(z0, z1);
#pragma unroll
    for (int o = 16; o; o >>= 1) m = fmaxf(m, __shfl_xor(m, o, 64));
    float pe = act ? (__expf(z0 - m) + __expf(z1 - m)) : 0.f;
#pragma unroll
    for (int o = 16; o; o >>= 1) pe += __shfl_xor(pe, o, 64);
    if (act){
        float l = __logf(pe);
        float2 o2 = make_float2(z0 - m - l, z1 - m - l);
        *(float2*)(out + (size_t)node * NC + 2 * hl) = o2;
    }
}

extern "C" void kernel_launch(void* const* d_in, const int* in_sizes, int n_in,
                              void* d_out, int out_size, void* d_ws, size_t ws_size,
                              hipStream_t stream) {
    const float* x    = (const float*)d_in[0];
    const int*   esrc = (const int*)  d_in[1];
    const int*   edst = (const int*)  d_in[2];
    const float* eval = (const float*)d_in[3];
    const float* W1   = (const float*)d_in[4];
    const float* b1   = (const float*)d_in[5];
    const float* W2   = (const float*)d_in[6];
    const float* b2   = (const float*)d_in[7];
    float* out = (float*)d_out;

    char* ws = (char*)d_ws;
    size_t off = 0;
    auto alloc = [&](size_t bytes) -> void* {
        void* p = ws + off;
        off += (bytes + 255) & ~(size_t)255;
        return p;
    };
    unsigned short* W1t  = (unsigned short*)alloc((size_t)NF * NH * 2);
    unsigned short* W2t  = (unsigned short*)alloc((size_t)48 * NH * 2);
    unsigned short* s1   = (unsigned short*)alloc((size_t)NN * NH * 2);
    unsigned short* h    = (unsigned short*)alloc((size_t)NN * NH * 2);
    unsigned short* s2p  = (unsigned short*)alloc((size_t)NN * 64 * 2);
    int*   deg   = (int*)  alloc((size_t)NN * 4);
    int*   rs    = (int*)  alloc((size_t)NN * 4);
    int*   bsums = (int*)  alloc(128 * 4);
    int*   posw  = (int*)  alloc((size_t)NE * 4);
    int2*  pk    = (int2*) alloc((size_t)NE * 8);

    hipMemsetAsync(deg, 0, (size_t)NN * 4, stream);

    hist_prep<<<280 + (NE + 255) / 256, 256, 0, stream>>>(edst, deg, posw, W1, W2, W1t, W2t);
    gemm1    <<<(NN + 127) / 128, 256, 0, stream>>>(x, W1t, s1);
    scan1    <<<98, 256, 0, stream>>>(deg, rs, bsums);
    scan3    <<<98, 256, 0, stream>>>(rs, bsums);
    scatter_k<<<(NE + 255) / 256, 256, 0, stream>>>(esrc, edst, eval, rs, posw, pk);
    agg1     <<<NN / 8, 256, 0, stream>>>((const uint2*)s1, rs, pk, b1, (uint2*)h);
    gemm2    <<<(NN + 63) / 64, 256, 0, stream>>>(h, W2t, s2p);
    agg2     <<<NN / 8, 256, 0, stream>>>((const unsigned*)s2p, rs, pk, b2, out);
}